// Round 5
// baseline (305.273 us; speedup 1.0000x reference)
//
#include <hip/hip_runtime.h>
#include <hip/hip_cooperative_groups.h>
#include <math.h>

namespace cg = cooperative_groups;

#define IN_NODES  4096
#define OUT_NODES 1024
#define ROW_ELEMS 16384          // floats per in-node row (1024*16)
#define ROW_C4    4096           // float4 chunks per row
#define ROW_U4    2048           // uint4 (8xbf16) chunks per row
#define NBLK      256
#define NTHR      512
#define PB        16             // in-node rows per block (4096/256)

typedef unsigned short u16;
typedef unsigned int   u32;

__device__ __forceinline__ float dot4(const float4 a, const float4 b) {
    return a.x*b.x + a.y*b.y + a.z*b.z + a.w*b.w;
}
__device__ __forceinline__ void fma4(float4& a, const float c, const float4 u) {
    a.x += c*u.x; a.y += c*u.y; a.z += c*u.z; a.w += c*u.w;
}
__device__ __forceinline__ void add4(float4& a, const float4 u) {
    a.x += u.x; a.y += u.y; a.z += u.z; a.w += u.w;
}
__device__ __forceinline__ u16 f2b(float x) {            // RNE f32->bf16
    u32 b = __float_as_uint(x);
    return (u16)((b + 0x7FFFu + ((b >> 16) & 1u)) >> 16);
}
__device__ __forceinline__ ushort4 f2b4(float4 v) {
    ushort4 r; r.x = f2b(v.x); r.y = f2b(v.y); r.z = f2b(v.z); r.w = f2b(v.w);
    return r;
}
// uint4 = 8 bf16 (memory order) -> two float4
__device__ __forceinline__ void unpack8(const uint4 w, float4& lo, float4& hi) {
    lo.x = __uint_as_float(w.x << 16);
    lo.y = __uint_as_float(w.x & 0xFFFF0000u);
    lo.z = __uint_as_float(w.y << 16);
    lo.w = __uint_as_float(w.y & 0xFFFF0000u);
    hi.x = __uint_as_float(w.z << 16);
    hi.y = __uint_as_float(w.z & 0xFFFF0000u);
    hi.z = __uint_as_float(w.w << 16);
    hi.w = __uint_as_float(w.w & 0xFFFF0000u);
}

// ---------------------------------------------------------------------------
// Distributed reduce of the 256 partial-s buffers + squash, inlined into the
// fused kernel between grid syncs. Each block owns 64 consecutive floats of
// the 16384-float s/V arrays; wave w sums partials b === w (mod 8) (4-stream
// ILP), LDS-combines the 8 wave sums, wave 0 squashes (16-lane f-groups).
// ---------------------------------------------------------------------------
__device__ __forceinline__ void reduce_phase(const float* __restrict__ part,
                                             float* __restrict__ V,
                                             float* __restrict__ out,
                                             int blk, int wave, int lane,
                                             float sred[8][64],
                                             int first, int emit) {
    const float* pp = part + blk * 64 + lane;
    float s0 = 0.f, s1 = 0.f, s2 = 0.f, s3 = 0.f;
    for (int b = wave; b < NBLK; b += 32) {
        s0 += pp[(size_t)(b     ) * ROW_ELEMS];
        s1 += pp[(size_t)(b +  8) * ROW_ELEMS];
        s2 += pp[(size_t)(b + 16) * ROW_ELEMS];
        s3 += pp[(size_t)(b + 24) * ROW_ELEMS];
    }
    sred[wave][lane] = (s0 + s1) + (s2 + s3);
    __syncthreads();
    if (wave == 0) {
        float s = 0.f;
        #pragma unroll
        for (int w = 0; w < 8; ++w) s += sred[w][lane];
        float sq = s * s;                 // sum over the out-node's 16 f's
        sq += __shfl_xor(sq, 1);
        sq += __shfl_xor(sq, 2);
        sq += __shfl_xor(sq, 4);
        sq += __shfl_xor(sq, 8);
        const float scale = sq / ((1.0f + sq) * sqrtf(sq));
        const float v = s * scale;
        const int g = blk * 64 + lane;
        V[g] = first ? v : (V[g] + v);
        if (emit) out[g] = v;
    }
    __syncthreads();
}

// ---------------------------------------------------------------------------
// Fused 3-iteration routing: one cooperative kernel, 256 blocks x 512 thr
// (1 block/CU). Phases separated by grid.sync():
//   P0 uniform pass (reads f32 uh, writes bf16 copy + partial s)
//   R0 reduce+squash -> V
//   P1,P2 softmax passes (read bf16 copy, block softmax, partial s)
//   R1,R2 reduce+squash -> V accumulate; R2 emits out.
// ---------------------------------------------------------------------------
__global__ __launch_bounds__(NTHR)
void fused_route(const float* __restrict__ uh, u16* __restrict__ uh2,
                 float* __restrict__ part, float* __restrict__ V,
                 float* __restrict__ out) {
    cg::grid_group grid = cg::this_grid();
    const int t    = threadIdx.x;
    const int wave = t >> 6;
    const int lane = t & 63;
    const int blk  = blockIdx.x;

    __shared__ float red8[8];
    __shared__ float redS;
    __shared__ float sred[8][64];

    // ---------------- P0: uniform (c = 1/1024) + bf16 conversion ----------
    {
        const int c0 = (wave << 9) + lane;      // float4 chunk, j stride 64
        float4 acc[8];
        #pragma unroll
        for (int j = 0; j < 8; ++j) acc[j] = make_float4(0.f, 0.f, 0.f, 0.f);

        const float4* p = reinterpret_cast<const float4*>(uh)
                        + (size_t)blk * PB * ROW_C4 + c0;
        ushort4* q = reinterpret_cast<ushort4*>(uh2)
                   + (size_t)blk * PB * ROW_C4 + c0;
        for (int g = 0; g < PB; ++g) {
            float4 u[8];
            #pragma unroll
            for (int j = 0; j < 8; ++j) u[j] = p[j * 64];
            #pragma unroll
            for (int j = 0; j < 8; ++j) { add4(acc[j], u[j]); q[j * 64] = f2b4(u[j]); }
            p += ROW_C4; q += ROW_C4;
        }
        float4* sp = reinterpret_cast<float4*>(part) + (size_t)blk * ROW_C4 + c0;
        const float c = 1.0f / OUT_NODES;
        #pragma unroll
        for (int j = 0; j < 8; ++j) {
            acc[j].x *= c; acc[j].y *= c; acc[j].z *= c; acc[j].w *= c;
            sp[j * 64] = acc[j];
        }
    }
    grid.sync();
    reduce_phase(part, V, out, blk, wave, lane, sred, 1, 0);
    grid.sync();

    // ---------------- P1, P2: softmax passes over the bf16 copy -----------
    for (int it = 1; it < 3; ++it) {
        {
            const int u0 = (wave << 8) + lane;  // uint4 chunk, j stride 64
            float4 v[8];
            {
                const float4* vp = reinterpret_cast<const float4*>(V);
                #pragma unroll
                for (int j = 0; j < 4; ++j) {
                    v[2*j]   = vp[2 * (u0 + j * 64)];
                    v[2*j+1] = vp[2 * (u0 + j * 64) + 1];
                }
            }
            float4 acc[8];
            #pragma unroll
            for (int j = 0; j < 8; ++j) acc[j] = make_float4(0.f, 0.f, 0.f, 0.f);

            const uint4* p = reinterpret_cast<const uint4*>(uh2)
                           + (size_t)blk * PB * ROW_U4 + u0;
            uint4 cur[4];
            #pragma unroll
            for (int j = 0; j < 4; ++j) cur[j] = p[j * 64];

            for (int g = 0; g < PB; ++g) {
                // distance-1 prefetch of the next row
                uint4 nxt[4];
                const uint4* pn = p + ROW_U4;
                if (g + 1 < PB) {
                    #pragma unroll
                    for (int j = 0; j < 4; ++j) nxt[j] = pn[j * 64];
                }

                float4 f[8];
                #pragma unroll
                for (int j = 0; j < 4; ++j) unpack8(cur[j], f[2*j], f[2*j+1]);

                float d[4];
                #pragma unroll
                for (int j = 0; j < 4; ++j)
                    d[j] = dot4(f[2*j], v[2*j]) + dot4(f[2*j+1], v[2*j+1]);
                #pragma unroll
                for (int j = 0; j < 4; ++j) d[j] += __shfl_xor(d[j], 1);

                float e[4];
                float etot = 0.f;
                #pragma unroll
                for (int j = 0; j < 4; ++j) { e[j] = __expf(d[j]); etot += e[j]; }

                #pragma unroll
                for (int off = 32; off; off >>= 1) etot += __shfl_xor(etot, off);
                if (lane == 0) red8[wave] = etot;
                __syncthreads();
                if (wave == 0) {
                    float s = (lane < 8) ? red8[lane] : 0.f;
                    s += __shfl_xor(s, 4); s += __shfl_xor(s, 2); s += __shfl_xor(s, 1);
                    if (lane == 0) redS = s;
                }
                __syncthreads();
                const float inv = 2.0f / redS;   // each o counted 2x (lane pair)

                #pragma unroll
                for (int j = 0; j < 4; ++j) {
                    const float c = e[j] * inv;
                    fma4(acc[2*j],   c, f[2*j]);
                    fma4(acc[2*j+1], c, f[2*j+1]);
                }

                #pragma unroll
                for (int j = 0; j < 4; ++j) cur[j] = nxt[j];
                p = pn;
            }

            float4* sp = reinterpret_cast<float4*>(part) + (size_t)blk * ROW_C4;
            #pragma unroll
            for (int j = 0; j < 4; ++j) {
                sp[2 * (u0 + j * 64)]     = acc[2*j];
                sp[2 * (u0 + j * 64) + 1] = acc[2*j+1];
            }
        }
        grid.sync();
        reduce_phase(part, V, out, blk, wave, lane, sred, 0, it == 2);
        if (it < 2) grid.sync();
    }
}

// ===========================================================================
// Fallback (no cooperative / small workspace): separate f32 kernels.
// ===========================================================================
__global__ __launch_bounds__(512, 4) void fb_uniform(const float* __restrict__ uh,
                                                     float* __restrict__ part,
                                                     int per_block) {
    const int t  = threadIdx.x;
    const int c0 = ((t >> 6) << 9) + (t & 63);
    float4 acc[8];
    #pragma unroll
    for (int j = 0; j < 8; ++j) acc[j] = make_float4(0.f, 0.f, 0.f, 0.f);
    const float4* p = reinterpret_cast<const float4*>(uh)
                    + (size_t)blockIdx.x * per_block * ROW_C4 + c0;
    for (int g = 0; g < per_block; ++g) {
        #pragma unroll
        for (int j = 0; j < 8; ++j) add4(acc[j], p[j * 64]);
        p += ROW_C4;
    }
    const float c = 1.0f / OUT_NODES;
    float4* sp = reinterpret_cast<float4*>(part) + (size_t)blockIdx.x * ROW_C4 + c0;
    #pragma unroll
    for (int j = 0; j < 8; ++j) {
        acc[j].x *= c; acc[j].y *= c; acc[j].z *= c; acc[j].w *= c;
        sp[j * 64] = acc[j];
    }
}

__global__ __launch_bounds__(512, 4) void fb_soft(const float* __restrict__ uh,
                                                  const float* __restrict__ V,
                                                  float* __restrict__ part,
                                                  int per_block) {
    const int t    = threadIdx.x;
    const int wave = t >> 6;
    const int lane = t & 63;
    const int c0   = (wave << 9) + lane;
    __shared__ float red8[8];
    __shared__ float redS;

    float4 v[8];
    const float4* vp = reinterpret_cast<const float4*>(V) + c0;
    #pragma unroll
    for (int j = 0; j < 8; ++j) v[j] = vp[j * 64];

    float4 acc[8];
    #pragma unroll
    for (int j = 0; j < 8; ++j) acc[j] = make_float4(0.f, 0.f, 0.f, 0.f);

    const float4* p = reinterpret_cast<const float4*>(uh)
                    + (size_t)blockIdx.x * per_block * ROW_C4 + c0;
    for (int g = 0; g < per_block; ++g) {
        float4 u[8];
        #pragma unroll
        for (int j = 0; j < 8; ++j) u[j] = p[j * 64];
        float d[8];
        #pragma unroll
        for (int j = 0; j < 8; ++j) d[j] = dot4(u[j], v[j]);
        #pragma unroll
        for (int j = 0; j < 8; ++j) {
            d[j] += __shfl_xor(d[j], 1);
            d[j] += __shfl_xor(d[j], 2);
        }
        float e[8];
        float etot = 0.f;
        #pragma unroll
        for (int j = 0; j < 8; ++j) { e[j] = __expf(d[j]); etot += e[j]; }
        #pragma unroll
        for (int off = 32; off; off >>= 1) etot += __shfl_xor(etot, off);
        if (lane == 0) red8[wave] = etot;
        __syncthreads();
        if (wave == 0) {
            float s = (lane < 8) ? red8[lane] : 0.f;
            s += __shfl_xor(s, 4); s += __shfl_xor(s, 2); s += __shfl_xor(s, 1);
            if (lane == 0) redS = s;
        }
        __syncthreads();
        const float inv = 4.0f / redS;
        #pragma unroll
        for (int j = 0; j < 8; ++j) fma4(acc[j], e[j] * inv, u[j]);
        p += ROW_C4;
    }
    float4* sp = reinterpret_cast<float4*>(part) + (size_t)blockIdx.x * ROW_C4 + c0;
    #pragma unroll
    for (int j = 0; j < 8; ++j) sp[j * 64] = acc[j];
}

__global__ __launch_bounds__(256) void fb_reduce(const float* __restrict__ part,
                                                 float* __restrict__ V,
                                                 float* __restrict__ out,
                                                 int G, int first) {
    const int t    = threadIdx.x;
    const int gidx = blockIdx.x * 64 + (t >> 2);
    const int q    = t & 3;
    const float* p = part + gidx;
    float a0 = 0.f, a1 = 0.f;
    int b = q;
    for (; b + 4 < G; b += 8) {
        a0 += p[(size_t)(b    ) * ROW_ELEMS];
        a1 += p[(size_t)(b + 4) * ROW_ELEMS];
    }
    for (; b < G; b += 4) a0 += p[(size_t)b * ROW_ELEMS];
    float s = a0 + a1;
    s += __shfl_xor(s, 1);
    s += __shfl_xor(s, 2);
    float sq = s * s;
    sq += __shfl_xor(sq, 4);
    sq += __shfl_xor(sq, 8);
    sq += __shfl_xor(sq, 16);
    sq += __shfl_xor(sq, 32);
    const float scale = sq / ((1.0f + sq) * sqrtf(sq));
    const float v = s * scale;
    out[gidx] = v;
    V[gidx]   = first ? v : (V[gidx] + v);
}

// ---------------------------------------------------------------------------
extern "C" void kernel_launch(void* const* d_in, const int* in_sizes, int n_in,
                              void* d_out, int out_size, void* d_ws, size_t ws_size,
                              hipStream_t stream) {
    const float* uh  = (const float*)d_in[0];
    float*       out = (float*)d_out;

    char*  ws   = (char*)d_ws;
    float* V    = (float*)ws;                          // 64 KB
    float* part = (float*)(ws + 65536);                // 256 * 64 KB = 16 MB
    u16*   uh2  = (u16*)(ws + 65536 + (size_t)NBLK * ROW_ELEMS * 4);  // 128 MB

    const size_t need = 65536ull + (size_t)NBLK * ROW_ELEMS * 4ull
                      + (size_t)IN_NODES * ROW_ELEMS * 2ull;

    bool ok = false;
    if (ws_size >= need) {
        void* args[] = { (void*)&uh, (void*)&uh2, (void*)&part,
                         (void*)&V, (void*)&out };
        hipError_t e = hipLaunchCooperativeKernel((const void*)fused_route,
                                                  dim3(NBLK), dim3(NTHR),
                                                  args, 0, stream);
        ok = (e == hipSuccess);
    }

    if (!ok) {
        int G = 256;
        while (G > 4 && ws_size < 65536ull * (size_t)(G + 1)) G >>= 1;
        const int per_block = IN_NODES / G;
        fb_uniform<<<G, 512, 0, stream>>>(uh, part, per_block);
        fb_reduce<<<256, 256, 0, stream>>>(part, V, out, G, 1);
        for (int it = 1; it < 3; ++it) {
            fb_soft<<<G, 512, 0, stream>>>(uh, V, part, per_block);
            fb_reduce<<<256, 256, 0, stream>>>(part, V, out, G, it == 0);
        }
    }
}

// Round 6
// 162.046 us; speedup vs baseline: 1.8839x; 1.8839x over previous
//
#include <hip/hip_runtime.h>
#include <math.h>

#define IN_NODES  4096
#define OUT_NODES 1024
#define ROW_ELEMS 16384          // floats per in-node row
#define ROW_C4    4096           // float4 chunks per row
#define ROW_U4    2048           // uint4 (8xbf16) chunks per row
#define NG        256            // grid for streaming passes
#define PB        16             // rows per block (4096/256)

typedef unsigned short u16;
typedef unsigned int   u32;

__device__ __forceinline__ float dot4(const float4 a, const float4 b) {
    return a.x*b.x + a.y*b.y + a.z*b.z + a.w*b.w;
}
__device__ __forceinline__ void fma4(float4& a, const float c, const float4 u) {
    a.x += c*u.x; a.y += c*u.y; a.z += c*u.z; a.w += c*u.w;
}
__device__ __forceinline__ void add4(float4& a, const float4 u) {
    a.x += u.x; a.y += u.y; a.z += u.z; a.w += u.w;
}
__device__ __forceinline__ u16 f2b(float x) {            // RNE f32->bf16
    u32 b = __float_as_uint(x);
    return (u16)((b + 0x7FFFu + ((b >> 16) & 1u)) >> 16);
}
__device__ __forceinline__ ushort4 f2b4(float4 v) {
    ushort4 r; r.x = f2b(v.x); r.y = f2b(v.y); r.z = f2b(v.z); r.w = f2b(v.w);
    return r;
}
// uint4 = 8 bf16 (memory order) -> two float4
__device__ __forceinline__ void unpack8(const uint4 w, float4& lo, float4& hi) {
    lo.x = __uint_as_float(w.x << 16);
    lo.y = __uint_as_float(w.x & 0xFFFF0000u);
    lo.z = __uint_as_float(w.y << 16);
    lo.w = __uint_as_float(w.y & 0xFFFF0000u);
    hi.x = __uint_as_float(w.z << 16);
    hi.y = __uint_as_float(w.z & 0xFFFF0000u);
    hi.z = __uint_as_float(w.w << 16);
    hi.w = __uint_as_float(w.w & 0xFFFF0000u);
}

// ---------------------------------------------------------------------------
// K0: uniform pass (c = 1/1024) + bf16 copy. 256 blocks x 1024 thr
// (16 waves/CU). Thread owns float4 chunks c = wave*256 + j*64 + lane,
// j=0..3: f32 loads are contiguous 1KB/instr, bf16 stores contiguous
// 512B/instr. ~45 VGPR, no barriers.
// ---------------------------------------------------------------------------
__global__ __launch_bounds__(1024) void k_uniform(const float* __restrict__ uh,
                                                  u16* __restrict__ uh2,
                                                  float* __restrict__ part) {
    const int t    = threadIdx.x;
    const int wave = t >> 6;
    const int lane = t & 63;
    const int c0   = (wave << 8) + lane;

    float4 acc[4];
    #pragma unroll
    for (int j = 0; j < 4; ++j) acc[j] = make_float4(0.f, 0.f, 0.f, 0.f);

    const float4* p = reinterpret_cast<const float4*>(uh)
                    + (size_t)blockIdx.x * PB * ROW_C4 + c0;
    ushort4* q = reinterpret_cast<ushort4*>(uh2)
               + (size_t)blockIdx.x * PB * ROW_C4 + c0;

    for (int g = 0; g < PB; ++g) {
        float4 u[4];
        #pragma unroll
        for (int j = 0; j < 4; ++j) u[j] = p[j * 64];
        #pragma unroll
        for (int j = 0; j < 4; ++j) { add4(acc[j], u[j]); q[j * 64] = f2b4(u[j]); }
        p += ROW_C4; q += ROW_C4;
    }

    const float c = 1.0f / OUT_NODES;
    float4* sp = reinterpret_cast<float4*>(part) + (size_t)blockIdx.x * ROW_C4 + c0;
    #pragma unroll
    for (int j = 0; j < 4; ++j) {
        acc[j].x *= c; acc[j].y *= c; acc[j].z *= c; acc[j].w *= c;
        sp[j * 64] = acc[j];
    }
}

// ---------------------------------------------------------------------------
// K_soft: softmax pass over the bf16 copy. 256 blocks x 1024 thr (16 waves/CU,
// ~85 VGPR). Thread owns uint4 units u0 = wave*128 + lane and u0+64; unit u
// is half of out-node o = u>>1 (even/odd lane pairs share o -> shfl_xor(1)
// completes d[o]). Two rows per iteration share one barrier pair; next two
// rows are prefetched before the reduction so their loads are in flight
// across the barriers. Unpack is recomputed in the FMA phase (reg-lean).
// No max-subtraction: |d| <= ||V||*4sigma < ~15, f32 exp is safe.
// ---------------------------------------------------------------------------
__global__ __launch_bounds__(1024) void k_soft(const u16* __restrict__ uh2,
                                               const float* __restrict__ V,
                                               float* __restrict__ part) {
    const int t    = threadIdx.x;
    const int wave = t >> 6;
    const int lane = t & 63;
    const int u0   = (wave << 7) + lane;      // first uint4 unit (second +64)

    __shared__ float2 red16[16];
    __shared__ float2 redS;

    float4 v[4];
    {
        const float4* vp = reinterpret_cast<const float4*>(V);
        v[0] = vp[2 * u0];          v[1] = vp[2 * u0 + 1];
        v[2] = vp[2 * (u0 + 64)];   v[3] = vp[2 * (u0 + 64) + 1];
    }

    float4 acc[4];
    #pragma unroll
    for (int j = 0; j < 4; ++j) acc[j] = make_float4(0.f, 0.f, 0.f, 0.f);

    const uint4* p = reinterpret_cast<const uint4*>(uh2)
                   + (size_t)blockIdx.x * PB * ROW_U4 + u0;

    // cur = rows g, g+1 (units u0, u0+64 each)
    uint4 cur[4];
    cur[0] = p[0]; cur[1] = p[64];
    cur[2] = p[ROW_U4]; cur[3] = p[ROW_U4 + 64];

    for (int g = 0; g < PB; g += 2) {
        uint4 nxt[4];
        const uint4* pn = p + 2 * ROW_U4;
        if (g + 2 < PB) {
            nxt[0] = pn[0]; nxt[1] = pn[64];
            nxt[2] = pn[ROW_U4]; nxt[3] = pn[ROW_U4 + 64];
        }

        // dots (row a: cur[0],cur[1]; row b: cur[2],cur[3])
        float d[4];
        #pragma unroll
        for (int j = 0; j < 4; ++j) {
            float4 lo, hi;
            unpack8(cur[j], lo, hi);
            d[j] = dot4(lo, v[(j & 1) * 2]) + dot4(hi, v[(j & 1) * 2 + 1]);
        }
        #pragma unroll
        for (int j = 0; j < 4; ++j) d[j] += __shfl_xor(d[j], 1);

        float e[4];
        #pragma unroll
        for (int j = 0; j < 4; ++j) e[j] = __expf(d[j]);

        float ea = e[0] + e[1];       // row a partial denom (each o counted 2x)
        float eb = e[2] + e[3];       // row b
        #pragma unroll
        for (int off = 32; off; off >>= 1) {
            ea += __shfl_xor(ea, off);
            eb += __shfl_xor(eb, off);
        }
        if (lane == 0) red16[wave] = make_float2(ea, eb);
        __syncthreads();
        if (wave == 0) {
            float2 s = (lane < 16) ? red16[lane] : make_float2(0.f, 0.f);
            #pragma unroll
            for (int off = 8; off; off >>= 1) {
                s.x += __shfl_xor(s.x, off);
                s.y += __shfl_xor(s.y, off);
            }
            if (lane == 0) redS = s;
        }
        __syncthreads();
        const float inva = 2.0f / redS.x;
        const float invb = 2.0f / redS.y;

        // FMA phase: recompute unpack (saves 32 VGPR over caching)
        #pragma unroll
        for (int j = 0; j < 4; ++j) {
            float4 lo, hi;
            unpack8(cur[j], lo, hi);
            const float c = e[j] * ((j < 2) ? inva : invb);
            fma4(acc[(j & 1) * 2],     c, lo);
            fma4(acc[(j & 1) * 2 + 1], c, hi);
        }

        #pragma unroll
        for (int j = 0; j < 4; ++j) cur[j] = nxt[j];
        p = pn;
    }

    float4* sp = reinterpret_cast<float4*>(part) + (size_t)blockIdx.x * ROW_C4;
    sp[2 * u0]            = acc[0];
    sp[2 * u0 + 1]        = acc[1];
    sp[2 * (u0 + 64)]     = acc[2];
    sp[2 * (u0 + 64) + 1] = acc[3];
}

// ---------------------------------------------------------------------------
// Reduce partials -> s, squash -> v, out, cumulative V. 256 x 256; 4 threads
// per output element; quad shfl combine; 16-lane butterfly for sum-of-squares.
// ---------------------------------------------------------------------------
__global__ __launch_bounds__(256) void k_reduce(const float* __restrict__ part,
                                                float* __restrict__ V,
                                                float* __restrict__ out,
                                                int G, int first) {
    const int t    = threadIdx.x;
    const int gidx = blockIdx.x * 64 + (t >> 2);   // o*16 + f
    const int q    = t & 3;
    const float* p = part + gidx;
    float a0 = 0.f, a1 = 0.f;
    int b = q;
    for (; b + 4 < G; b += 8) {
        a0 += p[(size_t)(b    ) * ROW_ELEMS];
        a1 += p[(size_t)(b + 4) * ROW_ELEMS];
    }
    for (; b < G; b += 4) a0 += p[(size_t)b * ROW_ELEMS];
    float s = a0 + a1;
    s += __shfl_xor(s, 1);
    s += __shfl_xor(s, 2);

    float sq = s * s;
    sq += __shfl_xor(sq, 4);
    sq += __shfl_xor(sq, 8);
    sq += __shfl_xor(sq, 16);
    sq += __shfl_xor(sq, 32);

    const float scale = sq / ((1.0f + sq) * sqrtf(sq));
    const float v = s * scale;

    out[gidx] = v;
    V[gidx]   = first ? v : (V[gidx] + v);
}

// ===========================================================================
// f32 fallback (only if workspace is unexpectedly small): R2-style kernels.
// ===========================================================================
__global__ __launch_bounds__(1024) void fb_uniform(const float* __restrict__ uh,
                                                   float* __restrict__ part,
                                                   int per_block) {
    const int t  = threadIdx.x;
    const int c0 = ((t >> 6) << 8) + (t & 63);
    float4 acc[4];
    #pragma unroll
    for (int j = 0; j < 4; ++j) acc[j] = make_float4(0.f, 0.f, 0.f, 0.f);
    const float4* p = reinterpret_cast<const float4*>(uh)
                    + (size_t)blockIdx.x * per_block * ROW_C4 + c0;
    for (int g = 0; g < per_block; ++g) {
        #pragma unroll
        for (int j = 0; j < 4; ++j) add4(acc[j], p[j * 64]);
        p += ROW_C4;
    }
    const float c = 1.0f / OUT_NODES;
    float4* sp = reinterpret_cast<float4*>(part) + (size_t)blockIdx.x * ROW_C4 + c0;
    #pragma unroll
    for (int j = 0; j < 4; ++j) {
        acc[j].x *= c; acc[j].y *= c; acc[j].z *= c; acc[j].w *= c;
        sp[j * 64] = acc[j];
    }
}

__global__ __launch_bounds__(1024) void fb_soft(const float* __restrict__ uh,
                                                const float* __restrict__ V,
                                                float* __restrict__ part,
                                                int per_block) {
    const int t    = threadIdx.x;
    const int wave = t >> 6;
    const int lane = t & 63;
    const int c0   = (wave << 8) + lane;
    __shared__ float red16[16];
    __shared__ float redS;

    float4 v[4];
    const float4* vp = reinterpret_cast<const float4*>(V) + c0;
    #pragma unroll
    for (int j = 0; j < 4; ++j) v[j] = vp[j * 64];

    float4 acc[4];
    #pragma unroll
    for (int j = 0; j < 4; ++j) acc[j] = make_float4(0.f, 0.f, 0.f, 0.f);

    const float4* p = reinterpret_cast<const float4*>(uh)
                    + (size_t)blockIdx.x * per_block * ROW_C4 + c0;
    for (int g = 0; g < per_block; ++g) {
        float4 u[4];
        #pragma unroll
        for (int j = 0; j < 4; ++j) u[j] = p[j * 64];
        float d[4];
        #pragma unroll
        for (int j = 0; j < 4; ++j) d[j] = dot4(u[j], v[j]);
        #pragma unroll
        for (int j = 0; j < 4; ++j) {
            d[j] += __shfl_xor(d[j], 1);
            d[j] += __shfl_xor(d[j], 2);
        }
        float e[4];
        float etot = 0.f;
        #pragma unroll
        for (int j = 0; j < 4; ++j) { e[j] = __expf(d[j]); etot += e[j]; }
        #pragma unroll
        for (int off = 32; off; off >>= 1) etot += __shfl_xor(etot, off);
        if (lane == 0) red16[wave] = etot;
        __syncthreads();
        if (wave == 0) {
            float s = (lane < 16) ? red16[lane] : 0.f;
            #pragma unroll
            for (int off = 8; off; off >>= 1) s += __shfl_xor(s, off);
            if (lane == 0) redS = s;
        }
        __syncthreads();
        const float inv = 4.0f / redS;
        #pragma unroll
        for (int j = 0; j < 4; ++j) fma4(acc[j], e[j] * inv, u[j]);
        p += ROW_C4;
    }
    float4* sp = reinterpret_cast<float4*>(part) + (size_t)blockIdx.x * ROW_C4 + c0;
    #pragma unroll
    for (int j = 0; j < 4; ++j) sp[j * 64] = acc[j];
}

// ---------------------------------------------------------------------------
extern "C" void kernel_launch(void* const* d_in, const int* in_sizes, int n_in,
                              void* d_out, int out_size, void* d_ws, size_t ws_size,
                              hipStream_t stream) {
    const float* uh  = (const float*)d_in[0];
    float*       out = (float*)d_out;

    char*  ws   = (char*)d_ws;
    float* V    = (float*)ws;                              // 64 KB
    float* part = (float*)(ws + 65536);                    // 256*64KB = 16 MB
    u16*   uh2  = (u16*)(ws + 65536 + (size_t)NG * ROW_ELEMS * 4);  // 128 MB

    const size_t need = 65536ull + (size_t)NG * ROW_ELEMS * 4ull
                      + (size_t)IN_NODES * ROW_ELEMS * 2ull;

    if (ws_size >= need) {
        k_uniform<<<NG, 1024, 0, stream>>>(uh, uh2, part);
        k_reduce<<<256, 256, 0, stream>>>(part, V, out, NG, 1);
        for (int it = 1; it < 3; ++it) {
            k_soft<<<NG, 1024, 0, stream>>>(uh2, V, part);
            k_reduce<<<256, 256, 0, stream>>>(part, V, out, NG, 0);
        }
    } else {
        int G2 = 256;
        while (G2 > 4 && ws_size < 65536ull * (size_t)(G2 + 1)) G2 >>= 1;
        const int per_block = IN_NODES / G2;
        fb_uniform<<<G2, 1024, 0, stream>>>(uh, part, per_block);
        k_reduce<<<256, 256, 0, stream>>>(part, V, out, G2, 1);
        for (int it = 1; it < 3; ++it) {
            fb_soft<<<G2, 1024, 0, stream>>>(uh, V, part, per_block);
            k_reduce<<<256, 256, 0, stream>>>(part, V, out, G2, 0);
        }
    }
}